// Round 3
// baseline (222.114 us; speedup 1.0000x reference)
//
#include <hip/hip_runtime.h>

// out[b,h,w,c] = t1*w0[c] + t2*w1[c] + t3*w2[c]
// N = 67,108,864 fp32; memory-bound streaming. Ideal traffic 1.073 GB.
// R1: plain float4 grid-stride, 2048 blocks -> 219 us (4.9 TB/s effective).
// R2: nt stores + x2 unroll -> neutral/worse (FETCH unchanged; L3 is
//     memory-side, nt hint doesn't free it). Reverted.
// R3: same body as R1, 4096 blocks x 16 iters — halve the drain-tail
//     quantum / finer XCD load balance. Everything else identical.

typedef float f32x4 __attribute__((ext_vector_type(4)));

__global__ __launch_bounds__(256) void merge3_kernel(
    const f32x4* __restrict__ t1,
    const f32x4* __restrict__ t2,
    const f32x4* __restrict__ t3,
    const float* __restrict__ weights,   // (C=256, 3) row-major
    f32x4* __restrict__ out,
    int n4)
{
    const int tid    = blockIdx.x * blockDim.x + threadIdx.x;
    const int stride = gridDim.x * blockDim.x;   // multiple of 256 -> mult of 64

    // Channel quad fixed across grid-stride iterations (stride % 64 == 0):
    const int cbase = (tid & 63) * 4;
    float w0[4], w1[4], w2[4];
    #pragma unroll
    for (int k = 0; k < 4; ++k) {
        w0[k] = weights[(cbase + k) * 3 + 0];
        w1[k] = weights[(cbase + k) * 3 + 1];
        w2[k] = weights[(cbase + k) * 3 + 2];
    }

    for (int i = tid; i < n4; i += stride) {
        f32x4 a = t1[i];
        f32x4 b = t2[i];
        f32x4 c = t3[i];
        f32x4 o;
        #pragma unroll
        for (int k = 0; k < 4; ++k)
            o[k] = fmaf(a[k], w0[k], fmaf(b[k], w1[k], c[k] * w2[k]));
        out[i] = o;
    }
}

extern "C" void kernel_launch(void* const* d_in, const int* in_sizes, int n_in,
                              void* d_out, int out_size, void* d_ws, size_t ws_size,
                              hipStream_t stream) {
    const f32x4* t1 = (const f32x4*)d_in[0];
    const f32x4* t2 = (const f32x4*)d_in[1];
    const f32x4* t3 = (const f32x4*)d_in[2];
    const float* w  = (const float*)d_in[3];
    f32x4* out = (f32x4*)d_out;

    const int n4 = out_size / 4;   // 16,777,216

    // 4096 blocks x 256 threads; each thread does 16 float4 iterations.
    // Finer tail granularity than 2048x32; stride still a multiple of 64
    // float4s so the per-thread channel quad stays fixed.
    dim3 grid(4096), block(256);
    merge3_kernel<<<grid, block, 0, stream>>>(t1, t2, t3, w, out, n4);
}